// Round 15
// baseline (576.600 us; speedup 1.0000x reference)
//
#include <hip/hip_runtime.h>
#include <math.h>

#define NN 4096
#define DD 512
#define NSL 16
#define SCALE_F 0.044194173824159216f
#define LN_EPS_F 1e-5f
#define ATTN_EPS_F 1e-8f

typedef float4 f4;
typedef __fp16 h2 __attribute__((ext_vector_type(2)));
typedef _Float16 h2f __attribute__((ext_vector_type(2)));
typedef _Float16 h8 __attribute__((ext_vector_type(8)));
typedef float f32x4 __attribute__((ext_vector_type(4)));

__device__ __forceinline__ float dot4f(f4 a, f4 b){
    return a.x*b.x + a.y*b.y + a.z*b.z + a.w*b.w;
}
__device__ __forceinline__ float fdot2u(unsigned a, unsigned b, float c){
    return __builtin_amdgcn_fdot2(__builtin_bit_cast(h2f, a),
                                  __builtin_bit_cast(h2f, b), c, false);
}
__device__ __forceinline__ unsigned pk(float x, float y){
    return __builtin_bit_cast(unsigned, __builtin_amdgcn_cvt_pkrtz(x, y));
}

// ---- prep: slots bcast + row stats + f16 copies of k,v + weight transpose ----
__global__ __launch_bounds__(256) void k_prep(const float* __restrict__ mu,
        const float* __restrict__ kin, const float* __restrict__ vin,
        float* __restrict__ slots, __fp16* __restrict__ slotsh,
        float* __restrict__ kmu, float* __restrict__ krstd,
        float* __restrict__ vmu, float* __restrict__ vrstd,
        __fp16* __restrict__ kh, __fp16* __restrict__ vh,
        const float* __restrict__ Wq, const float* __restrict__ Wih,
        const float* __restrict__ Whh, const float* __restrict__ W1,
        const float* __restrict__ W2,
        uint2* __restrict__ TWq, uint2* __restrict__ TWih, uint2* __restrict__ TWhh,
        uint2* __restrict__ TW1, uint2* __restrict__ TW2){
    int bx = blockIdx.x, t = threadIdx.x;
    int gid = bx*256 + t;
    if (bx < 128){
        int idx = gid;                             // 32768 f4
        f4 v = ((const f4*)mu)[idx & 2047];
        ((f4*)slots)[idx] = v;
        uint2 o; o.x = pk(v.x, v.y); o.y = pk(v.z, v.w);
        ((uint2*)slotsh)[idx] = o;
    }
    int sub = t & 15;
    int rl  = t >> 4;
#pragma unroll
    for (int pass = 0; pass < 8; pass++){
        int task = bx*128 + pass*16 + rl;          // 0..131071
        int half = task >> 16;                     // 0: v, 1: k
        int row  = task & 65535;
        const float* src = half ? kin : vin;
        __fp16* dsth = half ? kh : vh;
        const f4* r4 = (const f4*)(src + (size_t)row*DD);
        uint2* w2 = (uint2*)(dsth + (size_t)row*DD);
        float s = 0.f, ss = 0.f;
#pragma unroll
        for (int k2 = 0; k2 < 8; k2++){
            f4 x = r4[sub + k2*16];
            s  += x.x+x.y+x.z+x.w;
            ss += x.x*x.x+x.y*x.y+x.z*x.z+x.w*x.w;
            uint2 o; o.x = pk(x.x, x.y); o.y = pk(x.z, x.w);
            w2[sub + k2*16] = o;
        }
        for (int o = 1; o < 16; o <<= 1){
            s += __shfl_xor(s, o); ss += __shfl_xor(ss, o);
        }
        if (sub == 0){
            float m = s*(1.f/DD);
            float rs = rsqrtf(ss*(1.f/DD) - m*m + LN_EPS_F);
            if (half){ kmu[row] = m; krstd[row] = rs; }
            else     { vmu[row] = m; vrstd[row] = rs; }
        }
    }
    // weight transpose-pack (f16)
    for (int id = gid; id < 589824; id += 262144){
        const float* W; uint2* TW; int R, local;
        if (id < 65536)      { W = Wq;  TW = TWq;  R = 512;  local = id; }
        else if (id < 262144){ W = Wih; TW = TWih; R = 1536; local = id - 65536; }
        else if (id < 458752){ W = Whh; TW = TWhh; R = 1536; local = id - 262144; }
        else if (id < 524288){ W = W1;  TW = TW1;  R = 512;  local = id - 458752; }
        else                 { W = W2;  TW = TW2;  R = 512;  local = id - 524288; }
        int kk = local / R, c = local - kk*R;
        f4 w = ((const f4*)W)[(size_t)c*128 + kk];
        uint2 o; o.x = pk(w.x, w.y); o.y = pk(w.z, w.w);
        TW[local] = o;
    }
}

// ---- q0: initial q from broadcast slots_mu (16 unique rows), f32 precision ----
__global__ __launch_bounds__(256) void k_q0(const float* __restrict__ mu_,
        const float* __restrict__ Wq, const float* __restrict__ bq,
        const float* __restrict__ gs, const float* __restrict__ bs,
        const float* __restrict__ gk, const float* __restrict__ bk,
        __fp16* __restrict__ qgh, float* __restrict__ C1v, float* __restrict__ C2v){
    __shared__ __align__(16) float rowF[512];
    __shared__ float sm[16];
    int i = blockIdx.x, t = threadIdx.x, lane = t & 63, wv = t >> 6;
    float2 x = ((const float2*)(mu_ + (size_t)i*DD))[t];
    float s = x.x + x.y, ss = x.x*x.x + x.y*x.y;
    for (int o = 32; o; o >>= 1){ s += __shfl_down(s,o); ss += __shfl_down(ss,o); }
    if (lane == 0){ sm[wv] = s; sm[8+wv] = ss; }
    __syncthreads();
    s = sm[0]+sm[1]+sm[2]+sm[3]; ss = sm[8]+sm[9]+sm[10]+sm[11];
    float mu = s*(1.f/DD), rstd = rsqrtf(ss*(1.f/DD) - mu*mu + LN_EPS_F);
    rowF[2*t]   = (x.x-mu)*rstd*gs[2*t]   + bs[2*t];
    rowF[2*t+1] = (x.y-mu)*rstd*gs[2*t+1] + bs[2*t+1];
    __syncthreads();
    float c1p = 0.f, c2p = 0.f;
#pragma unroll
    for (int rep = 0; rep < 2; rep++){
        int c = t + rep*256;
        const f4* wrow = (const f4*)(Wq + (size_t)c*DD);
        const f4* rf = (const f4*)rowF;
        float acc = 0.f;
        for (int k = 0; k < 128; k++) acc += dot4f(rf[k], wrow[k]);
        float q0 = acc + bq[c];
        float qg = q0 * gk[c];
        __fp16 qh = (__fp16)qg;
        for (int b = 0; b < 16; b++)
            qgh[((size_t)(b*16+i))*DD + c] = qh;
        c1p += qg; c2p += q0*bk[c];
    }
    for (int o = 32; o; o >>= 1){ c1p += __shfl_down(c1p,o); c2p += __shfl_down(c2p,o); }
    if (lane == 0){ sm[wv] = c1p; sm[8+wv] = c2p; }
    __syncthreads();
    if (t == 0){
        float r1 = sm[0]+sm[1]+sm[2]+sm[3];
        float r2 = sm[8]+sm[9]+sm[10]+sm[11];
        for (int b = 0; b < 16; b++){ C1v[b*16+i] = r1; C2v[b*16+i] = r2; }
    }
}

// ---- fused QK^T (MFMA) + inverted softmax + AV partial (paired fdot2) ----
__global__ __launch_bounds__(256, 4) void k_attn_av(const __fp16* __restrict__ kh,
        const __fp16* __restrict__ vh, const __fp16* __restrict__ qgh,
        const float* __restrict__ C1v, const float* __restrict__ C2v,
        const float* __restrict__ kmu, const float* __restrict__ krstd,
        const float* __restrict__ vmu, const float* __restrict__ vrstd,
        float* __restrict__ Sp, float* __restrict__ Mp, __fp16* __restrict__ Uwp,
        float* __restrict__ attn_out, int last){
    __shared__ __align__(16) unsigned qLr[16*260];
    __shared__ __align__(16) unsigned wLp[32*20];
    __shared__ float c1s[NSL], c2s[NSL];
    __shared__ float kmuL[64], krsL[64], vmuL[64], vrsL[64];
    __shared__ float spL[4][NSL], mpL[4][NSL];
    int chunk = blockIdx.x, b = blockIdx.y;
    int t = threadIdx.x, lane = t & 63, wv = t >> 6;

    const unsigned* qsrc = (const unsigned*)(qgh + (size_t)b*NSL*DD);
    for (int e = t; e < 4096; e += 256)
        qLr[(e >> 8)*260 + (e & 255)] = qsrc[e];
    if (t < NSL){ c1s[t] = C1v[b*NSL + t]; c2s[t] = C2v[b*NSL + t]; }
    {
        int grp = t >> 6, j0 = t & 63;
        size_t gidx = (size_t)b*NN + chunk*64 + j0;
        if (grp == 0) kmuL[j0] = kmu[gidx];
        else if (grp == 1) krsL[j0] = krstd[gidx];
        else if (grp == 2) vmuL[j0] = vmu[gidx];
        else vrsL[j0] = vrstd[gidx];
    }
    __syncthreads();

    int i = lane & 15, g = lane >> 4;
    int jbase = chunk*64 + wv*16;
    const uint4* ka = (const uint4*)(kh + ((size_t)b*NN + jbase + i)*DD);
    const uint4* qb4 = (const uint4*)qLr;
    f32x4 acc = {0.f, 0.f, 0.f, 0.f};
#pragma unroll
    for (int ks = 0; ks < 16; ks++){
        uint4 af = ka[ks*4 + g];
        uint4 bf = qb4[i*65 + ks*4 + g];
        acc = __builtin_amdgcn_mfma_f32_16x16x32_f16(
                  __builtin_bit_cast(h8, af), __builtin_bit_cast(h8, bf), acc, 0, 0, 0);
    }
    float c1i = c1s[i], c2i = c2s[i];
    float a4[4], w4v[4];
    float S_part = 0.f, M_part = 0.f;
#pragma unroll
    for (int r = 0; r < 4; r++){
        int jl = g*4 + r;
        float mu = kmuL[wv*16 + jl], rstd = krsL[wv*16 + jl];
        float dv = SCALE_F*(rstd*(acc[r] - mu*c1i) + c2i);
        float mx = dv;
        mx = fmaxf(mx, __shfl_xor(mx, 1));
        mx = fmaxf(mx, __shfl_xor(mx, 2));
        mx = fmaxf(mx, __shfl_xor(mx, 4));
        mx = fmaxf(mx, __shfl_xor(mx, 8));
        float e = __expf(dv - mx);
        float se = e;
        se += __shfl_xor(se, 1);
        se += __shfl_xor(se, 2);
        se += __shfl_xor(se, 4);
        se += __shfl_xor(se, 8);
        float a = e/se + ATTN_EPS_F;
        a4[r] = a;
        float rv = vrsL[wv*16 + jl], vm = vmuL[wv*16 + jl];
        w4v[r] = a*rv;
        S_part += a;
        M_part += a*rv*vm;
    }
    wLp[(wv*8 + g*2)*20 + i]     = pk(w4v[0], w4v[1]);
    wLp[(wv*8 + g*2 + 1)*20 + i] = pk(w4v[2], w4v[3]);
    S_part += __shfl_xor(S_part, 16);
    S_part += __shfl_xor(S_part, 32);
    M_part += __shfl_xor(M_part, 16);
    M_part += __shfl_xor(M_part, 32);
    if (lane < 16){ spL[wv][lane] = S_part; mpL[wv][lane] = M_part; }
    if (last){
#pragma unroll
        for (int r = 0; r < 4; r++)
            attn_out[((size_t)b*NSL + i)*NN + jbase + g*4 + r] = a4[r];
    }
    __syncthreads();

    if (t < NSL)
        Sp[((size_t)b*NSL + t)*64 + chunk] = spL[0][t]+spL[1][t]+spL[2][t]+spL[3][t];
    else if (t < 2*NSL){
        int ii = t - NSL;
        Mp[((size_t)b*NSL + ii)*64 + chunk] = mpL[0][ii]+mpL[1][ii]+mpL[2][ii]+mpL[3][ii];
    }

    f4 ax[4], ay[4];
#pragma unroll
    for (int g2 = 0; g2 < 4; g2++){ ax[g2] = f4{0,0,0,0}; ay[g2] = f4{0,0,0,0}; }
    const unsigned* v2h = (const unsigned*)(vh + ((size_t)b*NN + (size_t)chunk*64)*DD);
#pragma unroll 2
    for (int p = 0; p < 32; p++){
        unsigned vu0 = v2h[(size_t)(2*p)*256 + t];
        unsigned vu1 = v2h[(size_t)(2*p+1)*256 + t];
        unsigned pd0 = __builtin_amdgcn_perm(vu1, vu0, 0x05040100u);
        unsigned pd1 = __builtin_amdgcn_perm(vu1, vu0, 0x07060302u);
        const uint4* wp4 = (const uint4*)(wLp + p*20);
#pragma unroll
        for (int g2 = 0; g2 < 4; g2++){
            uint4 w = wp4[g2];
            ax[g2].x = fdot2u(w.x, pd0, ax[g2].x);
            ax[g2].y = fdot2u(w.y, pd0, ax[g2].y);
            ax[g2].z = fdot2u(w.z, pd0, ax[g2].z);
            ax[g2].w = fdot2u(w.w, pd0, ax[g2].w);
            ay[g2].x = fdot2u(w.x, pd1, ay[g2].x);
            ay[g2].y = fdot2u(w.y, pd1, ay[g2].y);
            ay[g2].z = fdot2u(w.z, pd1, ay[g2].z);
            ay[g2].w = fdot2u(w.w, pd1, ay[g2].w);
        }
    }
#pragma unroll
    for (int g2 = 0; g2 < 4; g2++){
        const float* px = (const float*)&ax[g2];
        const float* py = (const float*)&ay[g2];
#pragma unroll
        for (int c4 = 0; c4 < 4; c4++){
            int ii = g2*4 + c4;
            ((unsigned*)Uwp)[(((size_t)(b*NSL + ii))*64 + chunk)*256 + t] = pk(px[c4], py[c4]);
        }
    }
}

// ---- updates = gv*(sum Uwp - M)/S + bv -> updh (f16) ----
__global__ __launch_bounds__(256) void k_upd(const __fp16* __restrict__ Uwp,
        const float* __restrict__ Sp, const float* __restrict__ Mp,
        const float* __restrict__ gv, const float* __restrict__ bv,
        __fp16* __restrict__ updh){
    __shared__ float sm[2];
    int m = blockIdx.x, t = threadIdx.x;
    if (t < 128){
        float val = (t < 64) ? Sp[(size_t)m*64 + (t&63)] : Mp[(size_t)m*64 + (t&63)];
        for (int o = 1; o < 64; o <<= 1) val += __shfl_xor(val, o);
        if (t == 0)  sm[0] = val;
        if (t == 64) sm[1] = val;
    }
    __syncthreads();
    float Sv = sm[0], Mv = sm[1];
    float rS = 1.f/Sv;
    float accx = 0.f, accy = 0.f;
    const unsigned* base = (const unsigned*)Uwp + (size_t)m*64*256 + t;
#pragma unroll 8
    for (int ch = 0; ch < 64; ch++){
        h2 u = __builtin_bit_cast(h2, base[(size_t)ch*256]);
        accx += (float)u.x; accy += (float)u.y;
    }
    float2 gvv = ((const float2*)gv)[t];
    float2 bvv = ((const float2*)bv)[t];
    float ox = gvv.x*(accx - Mv)*rS + bvv.x;
    float oy = gvv.y*(accy - Mv)*rS + bvv.y;
    ((unsigned*)updh)[(size_t)m*256 + t] = pk(ox, oy);
}

// ---- GRU gate matmuls, f16 + split-K x2: grid (32 cc, 16 mg, 2 ks) ----
__global__ __launch_bounds__(256) void k_gru_mm(const __fp16* __restrict__ xh, const __fp16* __restrict__ hh,
        const uint2* __restrict__ TWih, const float* __restrict__ bih,
        const uint2* __restrict__ TWhh, const float* __restrict__ bhh,
        float* __restrict__ gpA, float* __restrict__ gpB){
    int lane = threadIdx.x & 63, wv = threadIdx.x >> 6;
    int c = blockIdx.x*64 + lane;
    int m0 = blockIdx.y*16 + wv*4;
    int ks = blockIdx.z;
    int k0 = ks*64, k1 = k0 + 64;
    float* gp = ks ? gpB : gpA;
    int type = c >> 9;
    const uint2* x2 = (const uint2*)xh;
    const uint2* h2_ = (const uint2*)hh;
    float acc[4] = {0,0,0,0};
    float bias;
    if (type <= 1){
#pragma unroll 2
        for (int kk = k0; kk < k1; kk++){
            uint2 wa = TWih[(size_t)kk*1536 + c];
            uint2 wb = TWhh[(size_t)kk*1536 + c];
#pragma unroll
            for (int mm = 0; mm < 4; mm++){
                uint2 xa = x2[(size_t)(m0+mm)*128 + kk];
                uint2 ha = h2_[(size_t)(m0+mm)*128 + kk];
                acc[mm] = fdot2u(wa.x, xa.x, acc[mm]);
                acc[mm] = fdot2u(wa.y, xa.y, acc[mm]);
                acc[mm] = fdot2u(wb.x, ha.x, acc[mm]);
                acc[mm] = fdot2u(wb.y, ha.y, acc[mm]);
            }
        }
        bias = bih[c] + bhh[c];
    } else if (type == 2){
#pragma unroll 2
        for (int kk = k0; kk < k1; kk++){
            uint2 wa = TWih[(size_t)kk*1536 + c];
#pragma unroll
            for (int mm = 0; mm < 4; mm++){
                uint2 xa = x2[(size_t)(m0+mm)*128 + kk];
                acc[mm] = fdot2u(wa.x, xa.x, acc[mm]);
                acc[mm] = fdot2u(wa.y, xa.y, acc[mm]);
            }
        }
        bias = bih[c];
    } else {
        int cr = c - 512;
#pragma unroll 2
        for (int kk = k0; kk < k1; kk++){
            uint2 wb = TWhh[(size_t)kk*1536 + cr];
#pragma unroll
            for (int mm = 0; mm < 4; mm++){
                uint2 ha = h2_[(size_t)(m0+mm)*128 + kk];
                acc[mm] = fdot2u(wb.x, ha.x, acc[mm]);
                acc[mm] = fdot2u(wb.y, ha.y, acc[mm]);
            }
        }
        bias = bhh[cr];
    }
    float bout = ks ? 0.f : bias;
#pragma unroll
    for (int mm = 0; mm < 4; mm++)
        gp[(size_t)(m0+mm)*2048 + c] = acc[mm] + bout;
}

// ---- tail: GRU-elem + LNff + FFN1 + FFN2 + LNs + q-proj. block = row m. ----
__global__ __launch_bounds__(512) void k_tail(const float* __restrict__ gpA,
        const float* __restrict__ gpB, float* __restrict__ slots,
        const float* __restrict__ gff, const float* __restrict__ bff,
        const uint2* __restrict__ TW1, const float* __restrict__ b1,
        const uint2* __restrict__ TW2, const float* __restrict__ b2,
        const float* __restrict__ gs, const float* __restrict__ bs,
        const uint2* __restrict__ TWq, const float* __restrict__ bq,
        const float* __restrict__ gk, const float* __restrict__ bk,
        __fp16* __restrict__ slotsh, __fp16* __restrict__ qgh,
        float* __restrict__ C1v, float* __restrict__ C2v,
        float* __restrict__ out_slots, int last){
    __shared__ __align__(8) __fp16 rowL[512];
    __shared__ __align__(8) __fp16 hidL[512];
    __shared__ float sm[16];
    int m = blockIdx.x, t = threadIdx.x;
    int lane = t & 63, wv = t >> 6;                 // 8 waves
    const float* g0 = gpA + (size_t)m*2048;
    const float* g1 = gpB + (size_t)m*2048;
    float rp  = g0[t]       + g1[t];
    float zp  = g0[512+t]   + g1[512+t];
    float nx  = g0[1024+t]  + g1[1024+t];
    float nh_ = g0[1536+t]  + g1[1536+t];
    float h = slots[(size_t)m*DD + t];
    float r = 1.f/(1.f + __expf(-rp));
    float z = 1.f/(1.f + __expf(-zp));
    float n = tanhf(nx + r*nh_);
    float s2 = (1.f - z)*n + z*h;
    // LN(gff,bff) stats
    float s = s2, ss = s2*s2;
    for (int o = 32; o; o >>= 1){ s += __shfl_down(s,o); ss += __shfl_down(ss,o); }
    if (lane == 0){ sm[wv] = s; sm[8+wv] = ss; }
    __syncthreads();
    s  = sm[0]+sm[1]+sm[2]+sm[3]+sm[4]+sm[5]+sm[6]+sm[7];
    ss = sm[8]+sm[9]+sm[10]+sm[11]+sm[12]+sm[13]+sm[14]+sm[15];
    float mu = s*(1.f/DD), rstd = rsqrtf(ss*(1.f/DD) - mu*mu + LN_EPS_F);
    __syncthreads();                               // sm reusable
    rowL[t] = (__fp16)((s2-mu)*rstd*gff[t] + bff[t]);
    __syncthreads();
    // FFN1: output c = t
    const uint2* ffv = (const uint2*)rowL;
    float acc = 0.f;
#pragma unroll 4
    for (int kk = 0; kk < 128; kk++){
        uint2 w = TW1[(size_t)kk*512 + t];
        uint2 q = ffv[kk];
        acc = fdot2u(w.x, q.x, acc);
        acc = fdot2u(w.y, q.y, acc);
    }
    hidL[t] = (__fp16)fmaxf(acc + b1[t], 0.f);
    __syncthreads();
    // FFN2: output d = t
    const uint2* hv = (const uint2*)hidL;
    float acc2 = 0.f;
#pragma unroll 4
    for (int kk = 0; kk < 128; kk++){
        uint2 w = TW2[(size_t)kk*512 + t];
        uint2 q = hv[kk];
        acc2 = fdot2u(w.x, q.x, acc2);
        acc2 = fdot2u(w.y, q.y, acc2);
    }
    float v0 = s2 + acc2 + b2[t];
    slots[(size_t)m*DD + t] = v0;
    slotsh[(size_t)m*DD + t] = (__fp16)v0;
    if (last){
        out_slots[(size_t)m*DD + t] = v0;
        return;
    }
    // LN(gs,bs) + q-projection for the next iteration
    float s3 = v0, ss3 = v0*v0;
    for (int o = 32; o; o >>= 1){ s3 += __shfl_down(s3,o); ss3 += __shfl_down(ss3,o); }
    if (lane == 0){ sm[wv] = s3; sm[8+wv] = ss3; }
    __syncthreads();
    s3  = sm[0]+sm[1]+sm[2]+sm[3]+sm[4]+sm[5]+sm[6]+sm[7];
    ss3 = sm[8]+sm[9]+sm[10]+sm[11]+sm[12]+sm[13]+sm[14]+sm[15];
    float mu2 = s3*(1.f/DD), rstd2 = rsqrtf(ss3*(1.f/DD) - mu2*mu2 + LN_EPS_F);
    __syncthreads();
    rowL[t] = (__fp16)((v0-mu2)*rstd2*gs[t] + bs[t]);
    __syncthreads();
    float accq = 0.f;
#pragma unroll 4
    for (int kk = 0; kk < 128; kk++){
        uint2 w = TWq[(size_t)kk*512 + t];
        uint2 q = ffv[kk];
        accq = fdot2u(w.x, q.x, accq);
        accq = fdot2u(w.y, q.y, accq);
    }
    float q0 = accq + bq[t];
    float qg = q0 * gk[t];
    qgh[(size_t)m*DD + t] = (__fp16)qg;
    float c1 = qg, c2 = q0*bk[t];
    for (int o = 32; o; o >>= 1){ c1 += __shfl_down(c1,o); c2 += __shfl_down(c2,o); }
    if (lane == 0){ sm[wv] = c1; sm[8+wv] = c2; }
    __syncthreads();
    if (t == 0){
        C1v[m] = sm[0]+sm[1]+sm[2]+sm[3]+sm[4]+sm[5]+sm[6]+sm[7];
        C2v[m] = sm[8]+sm[9]+sm[10]+sm[11]+sm[12]+sm[13]+sm[14]+sm[15];
    }
}

// ---- features ----
__global__ __launch_bounds__(256) void k_features(const float* __restrict__ prompts, const float* __restrict__ slots,
        const float* __restrict__ attn, float* __restrict__ pf, float* __restrict__ sf, float* __restrict__ sf2){
    int b = blockIdx.y;
    int pbase = blockIdx.x*32;
    int t = threadIdx.x;
    __shared__ float al[NSL][33];
    for (int idx = t; idx < NSL*32; idx += 256){
        int i = idx >> 5, pp = idx & 31;
        al[i][pp] = attn[((size_t)b*NSL + i)*NN + pbase + pp];
    }
    float2 pr[NSL], sl[NSL];
    const float2* p2 = (const float2*)prompts;
    const float2* s2 = (const float2*)(slots + (size_t)b*NSL*DD);
#pragma unroll
    for (int i = 0; i < NSL; i++){ pr[i] = p2[i*256+t]; sl[i] = s2[i*256+t]; }
    __syncthreads();
    for (int pp = 0; pp < 32; pp++){
        float a0=0.f, a1=0.f, c0=0.f, c1=0.f;
#pragma unroll
        for (int i = 0; i < NSL; i++){
            float a = al[i][pp];
            a0 += a*pr[i].x; a1 += a*pr[i].y;
            c0 += a*sl[i].x; c1 += a*sl[i].y;
        }
        size_t o = ((size_t)b*NN + pbase + pp)*DD + 2*t;
        float2 pv; pv.x=a0; pv.y=a1;
        float2 sv; sv.x=c0; sv.y=c1;
        *(float2*)(pf + o)  = pv;
        *(float2*)(sf + o)  = sv;
        *(float2*)(sf2 + o) = sv;
    }
}

extern "C" void kernel_launch(void* const* d_in, const int* in_sizes, int n_in,
                              void* d_out, int out_size, void* d_ws, size_t ws_size,
                              hipStream_t stream) {
    const float* k_inp   = (const float*)d_in[2];
    const float* v_inp   = (const float*)d_in[3];
    const float* slots_mu= (const float*)d_in[4];
    const float* prompts = (const float*)d_in[5];
    const float* Wq      = (const float*)d_in[6];
    const float* bq      = (const float*)d_in[7];
    const float* W_ih    = (const float*)d_in[8];
    const float* b_ih    = (const float*)d_in[9];
    const float* W_hh    = (const float*)d_in[10];
    const float* b_hh    = (const float*)d_in[11];
    const float* W1      = (const float*)d_in[12];
    const float* b1      = (const float*)d_in[13];
    const float* W2      = (const float*)d_in[14];
    const float* b2      = (const float*)d_in[15];
    const float* gk      = (const float*)d_in[16];
    const float* bk      = (const float*)d_in[17];
    const float* gv      = (const float*)d_in[18];
    const float* bv      = (const float*)d_in[19];
    const float* gs      = (const float*)d_in[20];
    const float* bs      = (const float*)d_in[21];
    const float* gff     = (const float*)d_in[22];
    const float* bff     = (const float*)d_in[23];

    float* ws = (float*)d_ws;
    float* slots   = ws + 0;           // 131072
    float* gp      = ws + 131072;      // 524288 -> 655360
    float* C1v     = ws + 655360;      // 256
    float* C2v     = ws + 655616;      // 256
    float* kmu     = ws + 655872;      // 65536
    float* krstd   = ws + 721408;      // 65536
    float* vmu     = ws + 786944;      // 65536
    float* vrstd   = ws + 852480;      // 65536
    float* Sp      = ws + 918016;      // 16384
    float* Mp      = ws + 934400;      // 16384 -> 950784
    __fp16* slotsh = (__fp16*)(ws + 950784);    // 65536 float-slots
    __fp16* updh   = (__fp16*)(ws + 1016320);   // 65536
    __fp16* qgh    = (__fp16*)(ws + 1081856);   // 65536 -> 1147392
    uint2* TWqh  = (uint2*)(ws + 1147392);      // 131072 -> 1278464
    uint2* TWihh = (uint2*)(ws + 1278464);      // 393216 -> 1671680
    uint2* TWhhh = (uint2*)(ws + 1671680);      // 393216 -> 2064896
    uint2* TW1h  = (uint2*)(ws + 2064896);      // 131072 -> 2195968
    uint2* TW2h  = (uint2*)(ws + 2195968);      // 131072 -> 2327040 floats = 9.3 MB

    float* out      = (float*)d_out;
    float* attn_out = out + 131072;
    float* pf       = out + 1179648;
    float* sf       = pf + 33554432;
    float* sf2      = sf + 33554432;
    __fp16* Uwp     = (__fp16*)pf;           // 8.4M f16 scratch in pf region
    float* gpB      = pf + 16777216;         // 0.5M floats scratch in pf region
    __fp16* kh      = (__fp16*)sf;           // 67 MB f16 k in sf region
    __fp16* vh      = (__fp16*)sf2;          // 67 MB f16 v in sf2 region
    // pf/sf/sf2 scratch fully consumed before k_features overwrites those regions

    k_prep<<<1024, 256, 0, stream>>>(slots_mu, k_inp, v_inp, slots, slotsh,
                                     kmu, krstd, vmu, vrstd, kh, vh,
                                     Wq, W_ih, W_hh, W1, W2,
                                     TWqh, TWihh, TWhhh, TW1h, TW2h);
    k_q0<<<16, 256, 0, stream>>>(slots_mu, Wq, bq, gs, bs, gk, bk, qgh, C1v, C2v);

    for (int it = 0; it < 3; it++){
        int last = (it == 2);
        k_attn_av<<<dim3(64,16), 256, 0, stream>>>(kh, vh, qgh, C1v, C2v,
                                                   kmu, krstd, vmu, vrstd,
                                                   Sp, Mp, Uwp, attn_out, last);
        k_upd<<<256, 256, 0, stream>>>(Uwp, Sp, Mp, gv, bv, updh);
        k_gru_mm<<<dim3(32,16,2), 256, 0, stream>>>(updh, slotsh, TWihh, b_ih, TWhhh, b_hh, gp, gpB);
        k_tail<<<256, 512, 0, stream>>>(gp, gpB, slots, gff, bff, TW1h, b1, TW2h, b2,
                                        gs, bs, TWqh, bq, gk, bk,
                                        slotsh, qgh, C1v, C2v, out, last);
    }

    k_features<<<dim3(128,16), 256, 0, stream>>>(prompts, slots, attn_out, pf, sf, sf2);
}